// Round 2
// 114.932 us; speedup vs baseline: 1.0158x; 1.0158x over previous
//
#include <hip/hip_runtime.h>
#include <math.h>

// B=4, N=512, C=D=256, K=20, rows=2048
//
// ws layout (float offsets):
//   WtL [0, 65536)          W_l^T [c][d]
//   WtR [65536, 131072)
//   XL  [1048576, +524288)  [row][d] row-major
//   XRt [1572864, +524288)  [b][d][j] d-major
//   Av  [2097152, +2048)    dot(att, XL[row])
//   Bv  [2099200, +2048)    dot(att, XR[row])
//
// out (float): [0,40960) index_i | [40960,81920) index_j | [81920,122880) attention

__global__ __launch_bounds__(256) void k_transpose(const float* __restrict__ Wl,
                                                   const float* __restrict__ Wr,
                                                   float* __restrict__ WtL,
                                                   float* __restrict__ WtR) {
    const int d = blockIdx.x, c = threadIdx.x;  // coalesced read of W[d][:]
    if (blockIdx.y == 0) WtL[c * 256 + d] = Wl[d * 256 + c];
    else                 WtR[c * 256 + d] = Wr[d * 256 + c];
}

// 256 wgs x 512 thr; wg = 8 rows.
// R7: XRt emitted via 8KB LDS restage -> coalesced float4 stores (was 16x 4B
// scatter per ch0 thread = 64 line-splits per wave-store).
__global__ __launch_bounds__(512, 4) void k_proj(const float* __restrict__ x,
        const float* __restrict__ WtL, const float* __restrict__ WtR,
        const float* __restrict__ bl, const float* __restrict__ br,
        const float* __restrict__ att,
        float* __restrict__ XL, float* __restrict__ XRt,
        float* __restrict__ Av, float* __restrict__ Bv) {
    __shared__ __align__(16) float xst[256 * 12];   // x[c][r] at c*12+r
    __shared__ __align__(16) float mrg[3 * 4096];
    __shared__ __align__(16) float srs[8 * 256];    // x_r sums [r8][d] for XRt emit
    const int tid = threadIdx.x;
    const int dq = tid & 63;
    const int rq = (tid >> 6) & 1;
    const int ch = tid >> 7;           // 0..3
    const int R = blockIdx.x * 8;
    const int b = R >> 9, jr0 = R & 511;

    {
        const float4 xv = ((const float4*)(x + (size_t)R * 256))[tid];
        const int r = tid >> 6;
        const int c4 = (tid & 63) * 4;
        xst[(c4 + 0) * 12 + r] = xv.x;
        xst[(c4 + 1) * 12 + r] = xv.y;
        xst[(c4 + 2) * 12 + r] = xv.z;
        xst[(c4 + 3) * 12 + r] = xv.w;
    }
    __syncthreads();

    float aL[4][4], aR[4][4];
#pragma unroll
    for (int r = 0; r < 4; ++r)
#pragma unroll
        for (int k = 0; k < 4; ++k) { aL[r][k] = 0.f; aR[r][k] = 0.f; }

    const int c0 = ch * 64;
    const float* WLp = WtL + (size_t)c0 * 256 + dq * 4;
    const float* WRp = WtR + (size_t)c0 * 256 + dq * 4;
#pragma unroll 4
    for (int cc = 0; cc < 64; ++cc) {
        const float4 wl = *(const float4*)(WLp + (size_t)cc * 256);
        const float4 wr = *(const float4*)(WRp + (size_t)cc * 256);
        const float4 xv = *(const float4*)&xst[(c0 + cc) * 12 + rq * 4];
#define PROJ_R(r, XS)                                  \
        aL[r][0] = fmaf(XS, wl.x, aL[r][0]);           \
        aL[r][1] = fmaf(XS, wl.y, aL[r][1]);           \
        aL[r][2] = fmaf(XS, wl.z, aL[r][2]);           \
        aL[r][3] = fmaf(XS, wl.w, aL[r][3]);           \
        aR[r][0] = fmaf(XS, wr.x, aR[r][0]);           \
        aR[r][1] = fmaf(XS, wr.y, aR[r][1]);           \
        aR[r][2] = fmaf(XS, wr.z, aR[r][2]);           \
        aR[r][3] = fmaf(XS, wr.w, aR[r][3]);
        PROJ_R(0, xv.x)
        PROJ_R(1, xv.y)
        PROJ_R(2, xv.z)
        PROJ_R(3, xv.w)
#undef PROJ_R
    }

    if (ch > 0) {
        float* m = &mrg[(ch - 1) * 4096];
#pragma unroll
        for (int r = 0; r < 4; ++r) {
            const int r8 = rq * 4 + r;
            *(float4*)&m[(r8 * 2 + 0) * 256 + dq * 4] = make_float4(aL[r][0], aL[r][1], aL[r][2], aL[r][3]);
            *(float4*)&m[(r8 * 2 + 1) * 256 + dq * 4] = make_float4(aR[r][0], aR[r][1], aR[r][2], aR[r][3]);
        }
    }
    __syncthreads();

    float pa[4], pb[4];
    if (ch == 0) {
        const float4 bl4 = *(const float4*)&bl[dq * 4];
        const float4 br4 = *(const float4*)&br[dq * 4];
        const float4 at4 = *(const float4*)&att[dq * 4];
#pragma unroll
        for (int r = 0; r < 4; ++r) {
            const int r8 = rq * 4 + r;
            const float4 mL0 = *(const float4*)&mrg[(r8 * 2 + 0) * 256 + dq * 4];
            const float4 mL1 = *(const float4*)&mrg[4096 + (r8 * 2 + 0) * 256 + dq * 4];
            const float4 mL2 = *(const float4*)&mrg[8192 + (r8 * 2 + 0) * 256 + dq * 4];
            const float4 mR0 = *(const float4*)&mrg[(r8 * 2 + 1) * 256 + dq * 4];
            const float4 mR1 = *(const float4*)&mrg[4096 + (r8 * 2 + 1) * 256 + dq * 4];
            const float4 mR2 = *(const float4*)&mrg[8192 + (r8 * 2 + 1) * 256 + dq * 4];
            float4 sl, sr;
            sl.x = aL[r][0] + mL0.x + mL1.x + mL2.x + bl4.x;
            sl.y = aL[r][1] + mL0.y + mL1.y + mL2.y + bl4.y;
            sl.z = aL[r][2] + mL0.z + mL1.z + mL2.z + bl4.z;
            sl.w = aL[r][3] + mL0.w + mL1.w + mL2.w + bl4.w;
            sr.x = aR[r][0] + mR0.x + mR1.x + mR2.x + br4.x;
            sr.y = aR[r][1] + mR0.y + mR1.y + mR2.y + br4.y;
            sr.z = aR[r][2] + mR0.z + mR1.z + mR2.z + br4.z;
            sr.w = aR[r][3] + mR0.w + mR1.w + mR2.w + br4.w;
            *(float4*)&XL[(size_t)(R + r8) * 256 + dq * 4] = sl;
            *(float4*)&srs[r8 * 256 + dq * 4] = sr;     // stage for coalesced XRt emit
            pa[r] = at4.x * sl.x + at4.y * sl.y + at4.z * sl.z + at4.w * sl.w;
            pb[r] = at4.x * sr.x + at4.y * sr.y + at4.z * sr.z + at4.w * sr.w;
        }
    }
    __syncthreads();

    // coalesced XRt emit: thread -> (d = tid>>1, half = tid&1) writes 4 j's
    {
        const int d = tid >> 1;
        const int half = tid & 1;
        float4 o;
        o.x = srs[(half * 4 + 0) * 256 + d];
        o.y = srs[(half * 4 + 1) * 256 + d];
        o.z = srs[(half * 4 + 2) * 256 + d];
        o.w = srs[(half * 4 + 3) * 256 + d];
        *(float4*)&XRt[((size_t)(b * 256 + d)) * 512 + jr0 + half * 4] = o;
    }

    if (ch == 0) {
#pragma unroll
        for (int r = 0; r < 4; ++r) {
#pragma unroll
            for (int off = 32; off; off >>= 1) {
                pa[r] += __shfl_xor(pa[r], off);
                pb[r] += __shfl_xor(pb[r], off);
            }
        }
        if (dq == 0) {
#pragma unroll
            for (int r = 0; r < 4; ++r) {
                Av[R + rq * 4 + r] = pa[r];
                Bv[R + rq * 4 + r] = pb[r];
            }
        }
    }
}

// Fused pair + top-k + softmax. 256 wgs x 512 thr; wg = 8 rows x all 512 j.
// Thread: jc = tid&127 -> j-quad, h = tid>>7 -> d-quarter (64 d), ALL 8 i.
// R7: all four h-groups dump partials to mrg[4][8][512] (alph buffer removed,
// one barrier removed); finalize fused into top-k with lane-interleaved
// j-mapping j = t*64+lane -> conflict-free stride-4B LDS reads (old alph read
// at stride 32B was a 16-way bank conflict). Arithmetic order preserved:
// sum = h0+h1+h2+h3, then fmaf(0.4, sum, 0.6*(Ai+Bj)) -> bit-identical output.
__global__ __launch_bounds__(512, 2) void k_pair_topk(const float* __restrict__ XL,
        const float* __restrict__ XRt, const float* __restrict__ Av,
        const float* __restrict__ Bv, const float* __restrict__ att,
        float* __restrict__ out) {
    __shared__ __align__(16) float xls[8 * 256];     // 8 KB
    __shared__ __align__(16) float atts[256];        // 1 KB
    __shared__ __align__(16) float mrg[4 * 4096];    // 64 KB: partials [h][i*512+j]
    const int tid = threadIdx.x;       // 0..511
    const int jc = tid & 127;          // j-quad index
    const int h = tid >> 7;            // d-quarter 0..3 (wave-uniform)
    const int g = blockIdx.x;          // 0..255
    const int R = g * 8, b = R >> 9;

    // stage xl rows + att
    ((float4*)xls)[tid] = ((const float4*)(XL + (size_t)R * 256))[tid];
    if (tid < 64) ((float4*)atts)[tid] = ((const float4*)att)[tid];
    __syncthreads();

    const int dbase = h * 64;
    const float* __restrict__ xrp = XRt + (size_t)b * 131072 + (size_t)dbase * 512 + jc * 4;

    float acc[8][4];
#pragma unroll
    for (int i = 0; i < 8; ++i)
#pragma unroll
        for (int c = 0; c < 4; ++c) acc[i][c] = 0.f;

    float4 bufA[8], bufB[8];
#pragma unroll
    for (int dd = 0; dd < 8; ++dd) bufA[dd] = *(const float4*)(xrp + (size_t)dd * 512);

#pragma unroll
    for (int ch = 0; ch < 8; ++ch) {
        const float4* cur = (ch & 1) ? bufB : bufA;   // static under full unroll
        float4* nxt = (ch & 1) ? bufA : bufB;
        if (ch < 7) {
            const float* p = xrp + (size_t)(ch + 1) * 8 * 512;
#pragma unroll
            for (int dd = 0; dd < 8; ++dd) nxt[dd] = *(const float4*)(p + (size_t)dd * 512);
        }
        const int d0 = dbase + ch * 8;
        const float4 at0 = *(const float4*)&atts[d0];      // LDS b128 broadcast
        const float4 at1 = *(const float4*)&atts[d0 + 4];
#pragma unroll
        for (int i = 0; i < 8; ++i) {
            const float4 xa = *(const float4*)&xls[i * 256 + d0];
            const float4 xb = *(const float4*)&xls[i * 256 + d0 + 4];
#define PSTEP(XLC, ATC, XR4)                                       \
            acc[i][0] = fmaf(ATC, fabsf(XLC + XR4.x), acc[i][0]);   \
            acc[i][1] = fmaf(ATC, fabsf(XLC + XR4.y), acc[i][1]);   \
            acc[i][2] = fmaf(ATC, fabsf(XLC + XR4.z), acc[i][2]);   \
            acc[i][3] = fmaf(ATC, fabsf(XLC + XR4.w), acc[i][3]);
            PSTEP(xa.x, at0.x, cur[0])
            PSTEP(xa.y, at0.y, cur[1])
            PSTEP(xa.z, at0.z, cur[2])
            PSTEP(xa.w, at0.w, cur[3])
            PSTEP(xb.x, at1.x, cur[4])
            PSTEP(xb.y, at1.y, cur[5])
            PSTEP(xb.z, at1.z, cur[6])
            PSTEP(xb.w, at1.w, cur[7])
#undef PSTEP
        }
    }

    // ALL h-groups dump partials (balanced; float4 writes are conflict-free)
    {
        float* m = &mrg[h * 4096];
#pragma unroll
        for (int i = 0; i < 8; ++i)
            *(float4*)&m[i * 512 + jc * 4] = make_float4(acc[i][0], acc[i][1], acc[i][2], acc[i][3]);
    }
    __syncthreads();

    // fused finalize + top-20 + softmax: wave w handles row w (8 waves, 8 rows)
    // lane holds j = t*64 + lane for t=0..7 -> stride-4B LDS reads, no conflicts
    const int lane = tid & 63;
    const int i = tid >> 6;
    const float Ai = Av[R + i];
    const float* __restrict__ bvp = Bv + b * 512;
    const float* __restrict__ mr = &mrg[i * 512];
    float v[8];
#pragma unroll
    for (int t = 0; t < 8; ++t) {
        const int j = t * 64 + lane;
        float s = mr[j];              // h=0 partial
        s += mr[4096 + j];            // h=1
        s += mr[8192 + j];            // h=2
        s += mr[12288 + j];           // h=3
        float a = fmaf(0.4f, s, 0.6f * (Ai + bvp[j]));
        if (!isfinite(a)) a = 0.f;    // nan_to_num
        v[t] = a;
    }

    float myval = 0.f, mmax = 0.f;
    int myidx = 0;
    for (int sel = 0; sel < 20; ++sel) {
        float bv = v[0]; int bt = 0;
#pragma unroll
        for (int t = 1; t < 8; ++t) { if (v[t] > bv) { bv = v[t]; bt = t; } }
        int bj = bt * 64 + lane;      // j = t*64+lane; lowest t = lowest j per lane
#pragma unroll
        for (int off = 32; off; off >>= 1) {   // butterfly argmax, lower j wins ties
            const float ov = __shfl_xor(bv, off);
            const int   oj = __shfl_xor(bj, off);
            if (ov > bv || (ov == bv && oj < bj)) { bv = ov; bj = oj; }
        }
        if (sel == 0) mmax = bv;
        if (lane == sel) { myval = bv; myidx = bj; }
        if ((bj & 63) == lane) {
            const int bt2 = bj >> 6;
#pragma unroll
            for (int t = 0; t < 8; ++t) if (t == bt2) v[t] = -INFINITY;
        }
    }
    const float e = (lane < 20) ? expf(myval - mmax) : 0.f;
    float s = e;
#pragma unroll
    for (int off = 32; off; off >>= 1) s += __shfl_xor(s, off);
    if (lane < 20) {
        const int row = R + i;
        const int base = row * 20 + lane;
        out[base] = (float)row;                        // index_i
        out[40960 + base] = (float)(b * 512 + myidx);  // index_j
        out[81920 + base] = e / s;                     // attention
    }
}

extern "C" void kernel_launch(void* const* d_in, const int* in_sizes, int n_in,
                              void* d_out, int out_size, void* d_ws, size_t ws_size,
                              hipStream_t stream) {
    const float* x   = (const float*)d_in[0];
    const float* Wl  = (const float*)d_in[3];
    const float* bl  = (const float*)d_in[4];
    const float* Wr  = (const float*)d_in[5];
    const float* br  = (const float*)d_in[6];
    const float* att = (const float*)d_in[7];

    float* ws  = (float*)d_ws;
    float* WtL = ws;
    float* WtR = ws + 65536;
    float* XL  = ws + 1048576;
    float* XRt = ws + 1572864;
    float* Av  = ws + 2097152;
    float* Bv  = ws + 2099200;
    float* out = (float*)d_out;

    k_transpose<<<dim3(256, 2), dim3(256), 0, stream>>>(Wl, Wr, WtL, WtR);
    k_proj<<<dim3(256), dim3(512), 0, stream>>>(x, WtL, WtR, bl, br, att, XL, XRt, Av, Bv);
    k_pair_topk<<<dim3(256), dim3(512), 0, stream>>>(XL, XRt, Av, Bv, att, out);
}